// Round 2
// 299.462 us; speedup vs baseline: 1.0771x; 1.0771x over previous
//
#include <hip/hip_runtime.h>
#include <math.h>

#define BB    32
#define TT    1024
#define VV    1024
#define LM    128
#define SS    257        // 2*LM+1 extended states
#define SP    272        // floats per row = 1088 B = 17 full cache lines
#define RNORM 32         // renormalize every 32 DP steps (f64: huge margin)
#define PF    8          // DP prefetch ring depth (STATIC indices -> registers)
#define RPW   8          // rows per wave in the row kernel

// ---------------------------------------------------------------------------
// Kernel A (unchanged): one wave per 8 CONTIGUOUS rows, register
// double-buffered; fused online-softmax butterfly. Stores p = exp(x - mx)
// fp32 + slot257 = LSE - mx. Memory-bound (~30 us).
// ---------------------------------------------------------------------------
__global__ __launch_bounds__(256) void ctc_row_kernel(
    const float* __restrict__ ys_hat, const int* __restrict__ ys_pad,
    const int* __restrict__ hlens, float* __restrict__ lp)
{
    __shared__ float srow[4][VV];
    const int w    = threadIdx.x >> 6;
    const int lane = threadIdx.x & 63;
    const int gw   = blockIdx.x * 4 + w;      // 0..4095 global wave id
    const int b    = gw >> 7;                 // 128 waves per batch
    const int t0   = (gw & 127) * RPW;        // first frame of this wave
    const int hl   = hlens[b];
    int nrows = hl - t0;
    if (nrows <= 0) return;                   // wave-uniform exit
    if (nrows > RPW) nrows = RPW;

    const int lab0 = ys_pad[b * LM + 2 * lane];      // label for state 4l+1
    const int lab1 = ys_pad[b * LM + 2 * lane + 1];  // label for state 4l+3
    const float* xr  = ys_hat + ((size_t)b * TT + t0) * VV;
    float*       lpo = lp     + ((size_t)b * TT + t0) * SP;

    float4 va0, va1, va2, va3, vb0, vb1, vb2, vb3;
    {
        const float4* cx = (const float4*)xr;
        va0 = cx[lane]; va1 = cx[lane + 64]; va2 = cx[lane + 128]; va3 = cx[lane + 192];
    }

#define ROW_STEP(C0, C1, C2, C3, N0, N1, N2, N3)                               \
    {                                                                          \
        if (i + 1 < nrows) {  /* prefetch next row while we reduce this one */ \
            const float4* nx = (const float4*)(xr + (size_t)(i + 1) * VV);     \
            N0 = nx[lane]; N1 = nx[lane + 64];                                 \
            N2 = nx[lane + 128]; N3 = nx[lane + 192];                          \
        }                                                                      \
        float4* sw = (float4*)srow[w];                                         \
        sw[lane] = C0; sw[lane + 64] = C1;                                     \
        sw[lane + 128] = C2; sw[lane + 192] = C3;                              \
        float m = fmaxf(fmaxf(fmaxf(C0.x, C0.y), fmaxf(C0.z, C0.w)),          \
                        fmaxf(fmaxf(C1.x, C1.y), fmaxf(C1.z, C1.w)));          \
        m = fmaxf(m, fmaxf(fmaxf(fmaxf(C2.x, C2.y), fmaxf(C2.z, C2.w)),       \
                           fmaxf(fmaxf(C3.x, C3.y), fmaxf(C3.z, C3.w))));      \
        float s = __expf(C0.x - m) + __expf(C0.y - m) + __expf(C0.z - m) +     \
                  __expf(C0.w - m) + __expf(C1.x - m) + __expf(C1.y - m) +     \
                  __expf(C1.z - m) + __expf(C1.w - m) + __expf(C2.x - m) +     \
                  __expf(C2.y - m) + __expf(C2.z - m) + __expf(C2.w - m) +     \
                  __expf(C3.x - m) + __expf(C3.y - m) + __expf(C3.z - m) +     \
                  __expf(C3.w - m);                                            \
        _Pragma("unroll")                                                      \
        for (int off = 32; off; off >>= 1) {  /* fused max+sum butterfly */    \
            const float mo = __shfl_xor(m, off);                               \
            const float so = __shfl_xor(s, off);                               \
            const float mn = fmaxf(m, mo);                                     \
            s = s * __expf(m - mn) + so * __expf(mo - mn);                     \
            m = mn;                                                            \
        }                                                                      \
        const float xbv = srow[w][0];                                          \
        const float x1v = srow[w][lab0];                                       \
        const float x3v = srow[w][lab1];                                       \
        const float pb  = __expf(xbv - m);                                     \
        ((float4*)(lpo + (size_t)i * SP))[lane] =                              \
            make_float4(pb, __expf(x1v - m), pb, __expf(x3v - m));             \
        if (lane < 16) {  /* slots 256..271 = one full 64B line */             \
            float val = 0.f;                                                   \
            if (lane == 0) val = pb;            /* state 256 (blank) */        \
            if (lane == 1) val = __logf(s);     /* LSE - mx */                 \
            lpo[(size_t)i * SP + 256 + lane] = val;                            \
        }                                                                      \
    }

    int i = 0;
    for (;;) {
        ROW_STEP(va0, va1, va2, va3, vb0, vb1, vb2, vb3)
        if (++i >= nrows) break;
        ROW_STEP(vb0, vb1, vb2, vb3, va0, va1, va2, va3)
        if (++i >= nrows) break;
    }
#undef ROW_STEP
}

// ---------------------------------------------------------------------------
// VALU-only wave64 reduces via DPP row_shr. After shr 1/2/4/8 the FULL row
// result sits in lane 15 of each 16-lane row -> combine lanes 15/31/47/63
// via readlane. (v2 bug: read lanes 0/16/32/48 = partial prefixes.)
// bound_ctrl=true fills 0: identity-safe for add (any) and max (values >= 0).
// ---------------------------------------------------------------------------
#define DPP_ADDF(x, ctrl)                                                       \
    x = x + __int_as_float(__builtin_amdgcn_update_dpp(                         \
            0, __float_as_int(x), ctrl, 0xf, 0xf, true))
#define DPP_IMAX(x, ctrl)                                                       \
    {                                                                           \
        const int _o = __builtin_amdgcn_update_dpp(0, x, ctrl, 0xf, 0xf, true); \
        x = (x > _o) ? x : _o;                                                  \
    }
#define RLANEF(x, l) __int_as_float(__builtin_amdgcn_readlane(__float_as_int(x), (l)))
#define RLANEI(x, l) __builtin_amdgcn_readlane((x), (l))

// ---------------------------------------------------------------------------
// Kernel B: ONE WAVE PER BATCH, alpha in FP64 registers (4 states/lane,
// lane63 also owns state 256).
//  * cross-lane shfl SOFTWARE-PIPELINED one frame ahead: a3(t) (=c3n) depends
//    only on frame t-1 state, so it is computed first and shfl'd for frame
//    t+1 while frame t consumes the PREVIOUS shfl result -> the ~120cy
//    ds_bpermute latency overlaps a full frame of f64 work.
//  * renorm: per-lane f64 max -> HI-WORD int DPP max (monotonic for positive
//    doubles; NO f32 round-trip, alpha can be ~2^-320 between renorms) ->
//    EXACT 2^-k scale; integer ksum replaces clog += log(m).
//  * q.z == q.x (blank prob stored twice by kernel A); fma skip-adds;
//    a4 unmasked (garbage lanes follow a bounded state-like recurrence and
//    only feed the exactly-tracked renorm max).
//  * ss prologue: 16 unconditional batched loads, masked AFTER load via
//    select (rows >= hl are garbage; cndmask kills any bit pattern).
// ---------------------------------------------------------------------------
__global__ __launch_bounds__(64) void ctc_dp_kernel(
    const float* __restrict__ lp_all, const int* __restrict__ ys_pad,
    const int* __restrict__ hlens, const int* __restrict__ ys_lens,
    float* __restrict__ out)
{
    __shared__ double sh[SS];
    const int b    = blockIdx.x;
    const int lane = threadIdx.x;
    const int hl   = hlens[b];
    const float* lp = lp_all + (size_t)b * TT * SP;

    // ---- ss: sum of (LSE_t - mx_t) over t < hl, batched loads ----
    float sv[16];
#pragma unroll
    for (int jj = 0; jj < 16; ++jj)
        sv[jj] = lp[(size_t)(lane + jj * 64) * SP + 257];

    // ring prime overlaps the ss loads (hl >= 512 guarantees rows 1..PF)
    float4 qr[PF];
#pragma unroll
    for (int j = 0; j < PF; ++j)
        qr[j] = ((const float4*)(lp + (size_t)(1 + j) * SP))[lane];

    const int* lab = ys_pad + b * LM;
    const double sk1d = (lane > 0 && lab[2 * lane] != lab[2 * lane - 1]) ? 1.0 : 0.0;
    const double sk3d = (lab[2 * lane + 1] != lab[2 * lane]) ? 1.0 : 0.0;

    float ssv = 0.f;
#pragma unroll
    for (int jj = 0; jj < 16; ++jj)
        ssv += (lane + jj * 64 < hl) ? sv[jj] : 0.f;
    DPP_ADDF(ssv, 0x111); DPP_ADDF(ssv, 0x112); DPP_ADDF(ssv, 0x114); DPP_ADDF(ssv, 0x118);
    const float ssw = RLANEF(ssv, 15) + RLANEF(ssv, 31) + RLANEF(ssv, 47) + RLANEF(ssv, 63);

    // t = 0 init: only states 0 and 1 live (both in lane 0)
    const float4 q0 = ((const float4*)lp)[lane];
    double a0 = (lane == 0) ? (double)q0.x : 0.0;
    double a1 = (lane == 0) ? (double)q0.y : 0.0;
    double a2 = 0.0, a3 = 0.0, a4 = 0.0;
    double pn1 = 0.0;                 // pipelined shfl value: a3^{l-1}(0) == 0
    const bool lz = (lane == 0);
    int ksum = 0;

    for (int t0 = 1; t0 < hl; t0 += PF) {
#pragma unroll
        for (int j = 0; j < PF; ++j) {          // j static -> ring in VGPRs
            const int t = t0 + j;
            const float4 q = qr[j];
            int tp = t + PF; if (tp > hl - 1) tp = hl - 1;
            qr[j] = ((const float4*)(lp + (size_t)tp * SP))[lane];
            if (t < hl) {                        // wave-uniform
                if ((t & (RNORM - 1)) == 0) {    // rare, wave-uniform branch
                    double m = fmax(fmax(fmax(a0, a1), fmax(a2, a3)), a4);
                    m = fmax(m, 1e-300);         // denormal/zero guard
                    int hi = __double2hiint(m);  // sign=0: int cmp == mag cmp
                    DPP_IMAX(hi, 0x111); DPP_IMAX(hi, 0x112);
                    DPP_IMAX(hi, 0x114); DPP_IMAX(hi, 0x118);
                    const int h0 = RLANEI(hi, 15), h1 = RLANEI(hi, 31);
                    const int h2 = RLANEI(hi, 47), h3 = RLANEI(hi, 63);
                    int hw = (h0 > h1) ? h0 : h1;
                    hw = (hw > h2) ? hw : h2;
                    hw = (hw > h3) ? hw : h3;
                    const int k = (hw >> 20) - 1022;            // m = f*2^k, f in [0.5,1)
                    const double sc = __hiloint2double((1023 - k) << 20, 0); // exact 2^-k
                    ksum += k;                   // exact log tracking: ksum*ln2
                    a0 *= sc; a1 *= sc; a2 *= sc; a3 *= sc; a4 *= sc; pn1 *= sc;
                }
                const double qx = (double)q.x;
                const double qy = (double)q.y;
                const double qw = (double)q.w;   // q.z == q.x (blank): no cvt
                // next frame's boundary value first: depends only on OLD state
                const double c3n  = (a3 + fma(sk3d, a1, a2)) * qw;
                const double nraw = __shfl_up(c3n, 1);   // consumed NEXT frame
                const double n1 = lz ? 0.0 : pn1;        // previous frame's shfl
                const double c0 = (a0 + n1) * qx;
                const double c1 = fma(sk1d, n1, a0 + a1) * qy;
                const double c2 = (a2 + a1) * qx;
                const double c4 = (a4 + a3) * qx;  // state 256; lane63 meaningful
                a0 = c0; a1 = c1; a2 = c2; a3 = c3n; a4 = c4; pn1 = nraw;
            }
        }
    }

    sh[4 * lane]     = a0;
    sh[4 * lane + 1] = a1;
    sh[4 * lane + 2] = a2;
    sh[4 * lane + 3] = a3;
    if (lane == 63) sh[256] = a4;
    __syncthreads();                             // single wave
    if (lane == 0) {
        const int L = ys_lens[b];
        const double aL = sh[2 * L] + sh[2 * L - 1];
        const double loss = (double)ssw -
            (log(aL) + (double)ksum * 0.6931471805599453);
        atomicAdd(out, (float)(loss * (1.0 / (double)BB)));
    }
}

extern "C" void kernel_launch(void* const* d_in, const int* in_sizes, int n_in,
                              void* d_out, int out_size, void* d_ws, size_t ws_size,
                              hipStream_t stream) {
    const float* ys_hat  = (const float*)d_in[0];
    const int*   ys_pad  = (const int*)d_in[1];
    const int*   hlens   = (const int*)d_in[2];
    const int*   ys_lens = (const int*)d_in[3];
    float* out = (float*)d_out;

    float* lp_raw = (float*)d_ws;        // [B, T, SP] floats (~35.7 MB)

    hipMemsetAsync(d_out, 0, sizeof(float), stream);

    ctc_row_kernel<<<BB * TT / (4 * RPW), 256, 0, stream>>>(ys_hat, ys_pad, hlens, lp_raw);
    ctc_dp_kernel<<<BB, 64, 0, stream>>>(lp_raw, ys_pad, hlens, ys_lens, out);
}

// Round 3
// 266.195 us; speedup vs baseline: 1.2117x; 1.1250x over previous
//
#include <hip/hip_runtime.h>
#include <math.h>

#define BB    32
#define TT    1024
#define VV    1024
#define LM    128
#define SS    257        // 2*LM+1 extended states
#define SP    272        // floats per row = 1088 B = 17 full cache lines
#define RNORM 32         // renormalize every 32 DP steps (f64: huge margin)
#define PF    8          // DP prefetch ring depth (STATIC indices -> registers)
#define RPW   8          // rows per wave in the row kernel

// ---------------------------------------------------------------------------
// Kernel A (unchanged): one wave per 8 CONTIGUOUS rows, register
// double-buffered; fused online-softmax butterfly. Stores p = exp(x - mx)
// fp32 + slot257 = LSE - mx. Memory-bound (~30 us).
// ---------------------------------------------------------------------------
__global__ __launch_bounds__(256) void ctc_row_kernel(
    const float* __restrict__ ys_hat, const int* __restrict__ ys_pad,
    const int* __restrict__ hlens, float* __restrict__ lp)
{
    __shared__ float srow[4][VV];
    const int w    = threadIdx.x >> 6;
    const int lane = threadIdx.x & 63;
    const int gw   = blockIdx.x * 4 + w;      // 0..4095 global wave id
    const int b    = gw >> 7;                 // 128 waves per batch
    const int t0   = (gw & 127) * RPW;        // first frame of this wave
    const int hl   = hlens[b];
    int nrows = hl - t0;
    if (nrows <= 0) return;                   // wave-uniform exit
    if (nrows > RPW) nrows = RPW;

    const int lab0 = ys_pad[b * LM + 2 * lane];      // label for state 4l+1
    const int lab1 = ys_pad[b * LM + 2 * lane + 1];  // label for state 4l+3
    const float* xr  = ys_hat + ((size_t)b * TT + t0) * VV;
    float*       lpo = lp     + ((size_t)b * TT + t0) * SP;

    float4 va0, va1, va2, va3, vb0, vb1, vb2, vb3;
    {
        const float4* cx = (const float4*)xr;
        va0 = cx[lane]; va1 = cx[lane + 64]; va2 = cx[lane + 128]; va3 = cx[lane + 192];
    }

#define ROW_STEP(C0, C1, C2, C3, N0, N1, N2, N3)                               \
    {                                                                          \
        if (i + 1 < nrows) {  /* prefetch next row while we reduce this one */ \
            const float4* nx = (const float4*)(xr + (size_t)(i + 1) * VV);     \
            N0 = nx[lane]; N1 = nx[lane + 64];                                 \
            N2 = nx[lane + 128]; N3 = nx[lane + 192];                          \
        }                                                                      \
        float4* sw = (float4*)srow[w];                                         \
        sw[lane] = C0; sw[lane + 64] = C1;                                     \
        sw[lane + 128] = C2; sw[lane + 192] = C3;                              \
        float m = fmaxf(fmaxf(fmaxf(C0.x, C0.y), fmaxf(C0.z, C0.w)),          \
                        fmaxf(fmaxf(C1.x, C1.y), fmaxf(C1.z, C1.w)));          \
        m = fmaxf(m, fmaxf(fmaxf(fmaxf(C2.x, C2.y), fmaxf(C2.z, C2.w)),       \
                           fmaxf(fmaxf(C3.x, C3.y), fmaxf(C3.z, C3.w))));      \
        float s = __expf(C0.x - m) + __expf(C0.y - m) + __expf(C0.z - m) +     \
                  __expf(C0.w - m) + __expf(C1.x - m) + __expf(C1.y - m) +     \
                  __expf(C1.z - m) + __expf(C1.w - m) + __expf(C2.x - m) +     \
                  __expf(C2.y - m) + __expf(C2.z - m) + __expf(C2.w - m) +     \
                  __expf(C3.x - m) + __expf(C3.y - m) + __expf(C3.z - m) +     \
                  __expf(C3.w - m);                                            \
        _Pragma("unroll")                                                      \
        for (int off = 32; off; off >>= 1) {  /* fused max+sum butterfly */    \
            const float mo = __shfl_xor(m, off);                               \
            const float so = __shfl_xor(s, off);                               \
            const float mn = fmaxf(m, mo);                                     \
            s = s * __expf(m - mn) + so * __expf(mo - mn);                     \
            m = mn;                                                            \
        }                                                                      \
        const float xbv = srow[w][0];                                          \
        const float x1v = srow[w][lab0];                                       \
        const float x3v = srow[w][lab1];                                       \
        const float pb  = __expf(xbv - m);                                     \
        ((float4*)(lpo + (size_t)i * SP))[lane] =                              \
            make_float4(pb, __expf(x1v - m), pb, __expf(x3v - m));             \
        if (lane < 16) {  /* slots 256..271 = one full 64B line */             \
            float val = 0.f;                                                   \
            if (lane == 0) val = pb;            /* state 256 (blank) */        \
            if (lane == 1) val = __logf(s);     /* LSE - mx */                 \
            lpo[(size_t)i * SP + 256 + lane] = val;                            \
        }                                                                      \
    }

    int i = 0;
    for (;;) {
        ROW_STEP(va0, va1, va2, va3, vb0, vb1, vb2, vb3)
        if (++i >= nrows) break;
        ROW_STEP(vb0, vb1, vb2, vb3, va0, va1, va2, va3)
        if (++i >= nrows) break;
    }
#undef ROW_STEP
}

// ---------------------------------------------------------------------------
// VALU-only wave64 reduces via DPP row_shr: after shr 1/2/4/8 the FULL row
// result sits in lane 15 of each 16-lane row -> combine lanes 15/31/47/63.
// bound_ctrl=true fills 0: identity-safe for add (any) and max (values >= 0).
// ---------------------------------------------------------------------------
#define DPP_ADDF(x, ctrl)                                                       \
    x = x + __int_as_float(__builtin_amdgcn_update_dpp(                         \
            0, __float_as_int(x), ctrl, 0xf, 0xf, true))
#define DPP_IMAX(x, ctrl)                                                       \
    {                                                                           \
        const int _o = __builtin_amdgcn_update_dpp(0, x, ctrl, 0xf, 0xf, true); \
        x = (x > _o) ? x : _o;                                                  \
    }
#define RLANEF(x, l) __int_as_float(__builtin_amdgcn_readlane(__float_as_int(x), (l)))
#define RLANEI(x, l) __builtin_amdgcn_readlane((x), (l))

// Full-wave shift-down-by-1 (lane l gets lane l-1; lane 0 gets +0.0) as a
// pure-VALU op: gfx9-lineage DPP wave_shr:1 (ctrl 0x138), applied to both
// 32-bit halves of the double. Replaces __shfl_up(double) = 2x ds_bpermute
// (~120cy exposed DS latency, m117) with 2x v_mov_b32_dpp (~4cy).
// bound_ctrl=1 zero-fills lane 0 -> the (lane==0 ? 0.0 : ...) mask is free.
__device__ __forceinline__ double dpp_wave_shr1_f64(double x)
{
    const int lo = __builtin_amdgcn_update_dpp(
        0, __double2loint(x), 0x138, 0xf, 0xf, true);
    const int hi = __builtin_amdgcn_update_dpp(
        0, __double2hiint(x), 0x138, 0xf, 0xf, true);
    return __hiloint2double(hi, lo);
}

// ---------------------------------------------------------------------------
// Kernel B: ONE WAVE PER BATCH, alpha in FP64 registers (4 states/lane,
// lane63 also owns state 256).
//  * cross-lane a3 neighbor via DPP wave_shr:1 (VALU, same-frame consumption;
//    no DS ops, no pipelining register, no lane-0 mask needed).
//  * main loop is clamp-free (prefetch always valid, no t<hl check);
//    short clamped tail handles the last 8..15 frames.
//  * renorm: per-lane f64 max -> HI-WORD int DPP max (monotonic for positive
//    doubles) -> EXACT 2^-k scale; integer ksum replaces clog += log(m).
//  * q.z == q.x (blank prob stored twice by kernel A); fma skip-adds;
//    a4 unmasked (garbage lanes bounded, only feed the renorm max).
// ---------------------------------------------------------------------------
__global__ __launch_bounds__(64) void ctc_dp_kernel(
    const float* __restrict__ lp_all, const int* __restrict__ ys_pad,
    const int* __restrict__ hlens, const int* __restrict__ ys_lens,
    float* __restrict__ out)
{
    __shared__ double sh[SS];
    const int b    = blockIdx.x;
    const int lane = threadIdx.x;
    const int hl   = hlens[b];
    const float* lp = lp_all + (size_t)b * TT * SP;

    // ---- ss: sum of (LSE_t - mx_t) over t < hl, batched loads ----
    float sv[16];
#pragma unroll
    for (int jj = 0; jj < 16; ++jj)
        sv[jj] = lp[(size_t)(lane + jj * 64) * SP + 257];

    // ring prime overlaps the ss loads (hl >= 512 guarantees rows 1..PF)
    float4 qr[PF];
#pragma unroll
    for (int j = 0; j < PF; ++j)
        qr[j] = ((const float4*)(lp + (size_t)(1 + j) * SP))[lane];

    const int* lab = ys_pad + b * LM;
    const double sk1d = (lane > 0 && lab[2 * lane] != lab[2 * lane - 1]) ? 1.0 : 0.0;
    const double sk3d = (lab[2 * lane + 1] != lab[2 * lane]) ? 1.0 : 0.0;

    float ssv = 0.f;
#pragma unroll
    for (int jj = 0; jj < 16; ++jj)
        ssv += (lane + jj * 64 < hl) ? sv[jj] : 0.f;
    DPP_ADDF(ssv, 0x111); DPP_ADDF(ssv, 0x112); DPP_ADDF(ssv, 0x114); DPP_ADDF(ssv, 0x118);
    const float ssw = RLANEF(ssv, 15) + RLANEF(ssv, 31) + RLANEF(ssv, 47) + RLANEF(ssv, 63);

    // t = 0 init: only states 0 and 1 live (both in lane 0)
    const float4 q0 = ((const float4*)lp)[lane];
    double a0 = (lane == 0) ? (double)q0.x : 0.0;
    double a1 = (lane == 0) ? (double)q0.y : 0.0;
    double a2 = 0.0, a3 = 0.0, a4 = 0.0;
    int ksum = 0;

#define RENORM_BODY                                                            \
    {                                                                          \
        double m = fmax(fmax(fmax(a0, a1), fmax(a2, a3)), a4);                 \
        m = fmax(m, 1e-300);         /* denormal/zero guard */                 \
        int hi = __double2hiint(m);  /* sign=0: int cmp == mag cmp */          \
        DPP_IMAX(hi, 0x111); DPP_IMAX(hi, 0x112);                              \
        DPP_IMAX(hi, 0x114); DPP_IMAX(hi, 0x118);                              \
        const int h0 = RLANEI(hi, 15), h1 = RLANEI(hi, 31);                    \
        const int h2 = RLANEI(hi, 47), h3 = RLANEI(hi, 63);                    \
        int hw = (h0 > h1) ? h0 : h1;                                          \
        hw = (hw > h2) ? hw : h2;                                              \
        hw = (hw > h3) ? hw : h3;                                              \
        const int k = (hw >> 20) - 1022;            /* m = f*2^k, f in [0.5,1) */ \
        const double sc = __hiloint2double((1023 - k) << 20, 0); /* exact 2^-k */ \
        ksum += k;                   /* exact log tracking: ksum*ln2 */        \
        a0 *= sc; a1 *= sc; a2 *= sc; a3 *= sc; a4 *= sc;                      \
    }

#define DP_STEP(q)                                                             \
    {                                                                          \
        const double qx = (double)(q).x;                                       \
        const double qy = (double)(q).y;                                       \
        const double qw = (double)(q).w;   /* q.z == q.x (blank): no cvt */    \
        const double n1 = dpp_wave_shr1_f64(a3);  /* state 4l-1, lane0 -> 0 */ \
        const double c0 = (a0 + n1) * qx;                                      \
        const double c1 = fma(sk1d, n1, a0 + a1) * qy;                         \
        const double c2 = (a2 + a1) * qx;                                      \
        const double c3 = (a3 + fma(sk3d, a1, a2)) * qw;                       \
        const double c4 = (a4 + a3) * qx;  /* state 256; lane63 meaningful */  \
        a0 = c0; a1 = c1; a2 = c2; a3 = c3; a4 = c4;                           \
    }

    int t0 = 1;
    // main loop: all frames < hl and all prefetches <= hl-1 -> no clamps
    for (; t0 + 2 * PF - 1 <= hl - 1; t0 += PF) {
        const float* pf = lp + (size_t)(t0 + PF) * SP;
#pragma unroll
        for (int j = 0; j < PF; ++j) {          // j static -> ring in VGPRs
            const float4 q = qr[j];
            qr[j] = ((const float4*)(pf + (size_t)j * SP))[lane];
            if (((t0 + j) & (RNORM - 1)) == 0) RENORM_BODY
            DP_STEP(q)
        }
    }
    // tail: 8..15 frames, clamped prefetch, per-frame guard
    for (; t0 < hl; t0 += PF) {
#pragma unroll
        for (int j = 0; j < PF; ++j) {
            const int t = t0 + j;
            const float4 q = qr[j];
            int tp = t + PF; if (tp > hl - 1) tp = hl - 1;
            qr[j] = ((const float4*)(lp + (size_t)tp * SP))[lane];
            if (t < hl) {                        // wave-uniform
                if ((t & (RNORM - 1)) == 0) RENORM_BODY
                DP_STEP(q)
            }
        }
    }
#undef DP_STEP
#undef RENORM_BODY

    sh[4 * lane]     = a0;
    sh[4 * lane + 1] = a1;
    sh[4 * lane + 2] = a2;
    sh[4 * lane + 3] = a3;
    if (lane == 63) sh[256] = a4;
    __syncthreads();                             // single wave
    if (lane == 0) {
        const int L = ys_lens[b];
        const double aL = sh[2 * L] + sh[2 * L - 1];
        const double loss = (double)ssw -
            (log(aL) + (double)ksum * 0.6931471805599453);
        atomicAdd(out, (float)(loss * (1.0 / (double)BB)));
    }
}

extern "C" void kernel_launch(void* const* d_in, const int* in_sizes, int n_in,
                              void* d_out, int out_size, void* d_ws, size_t ws_size,
                              hipStream_t stream) {
    const float* ys_hat  = (const float*)d_in[0];
    const int*   ys_pad  = (const int*)d_in[1];
    const int*   hlens   = (const int*)d_in[2];
    const int*   ys_lens = (const int*)d_in[3];
    float* out = (float*)d_out;

    float* lp_raw = (float*)d_ws;        // [B, T, SP] floats (~35.7 MB)

    hipMemsetAsync(d_out, 0, sizeof(float), stream);

    ctc_row_kernel<<<BB * TT / (4 * RPW), 256, 0, stream>>>(ys_hat, ys_pad, hlens, lp_raw);
    ctc_dp_kernel<<<BB, 64, 0, stream>>>(lp_raw, ys_pad, hlens, ys_lens, out);
}

// Round 4
// 251.951 us; speedup vs baseline: 1.2802x; 1.0565x over previous
//
#include <hip/hip_runtime.h>
#include <math.h>

#define BB    32
#define TT    1024
#define VV    1024
#define LM    128
#define SS    257        // 2*LM+1 extended states
#define SP    272        // floats per row = 1088 B = 17 full cache lines
#define RNORM 16         // renormalize every 16 DP steps (f64: huge margin)
#define PF    16         // DP prefetch ring depth (STATIC indices -> registers)
#define RPW   8          // rows per wave in the row kernel

// ---------------------------------------------------------------------------
// Kernel A (unchanged): one wave per 8 CONTIGUOUS rows, register
// double-buffered; fused online-softmax butterfly. Stores p = exp(x - mx)
// fp32 + slot257 = LSE - mx. Memory-bound (~27 us).
// ---------------------------------------------------------------------------
__global__ __launch_bounds__(256) void ctc_row_kernel(
    const float* __restrict__ ys_hat, const int* __restrict__ ys_pad,
    const int* __restrict__ hlens, float* __restrict__ lp)
{
    __shared__ float srow[4][VV];
    const int w    = threadIdx.x >> 6;
    const int lane = threadIdx.x & 63;
    const int gw   = blockIdx.x * 4 + w;      // 0..4095 global wave id
    const int b    = gw >> 7;                 // 128 waves per batch
    const int t0   = (gw & 127) * RPW;        // first frame of this wave
    const int hl   = hlens[b];
    int nrows = hl - t0;
    if (nrows <= 0) return;                   // wave-uniform exit
    if (nrows > RPW) nrows = RPW;

    const int lab0 = ys_pad[b * LM + 2 * lane];      // label for state 4l+1
    const int lab1 = ys_pad[b * LM + 2 * lane + 1];  // label for state 4l+3
    const float* xr  = ys_hat + ((size_t)b * TT + t0) * VV;
    float*       lpo = lp     + ((size_t)b * TT + t0) * SP;

    float4 va0, va1, va2, va3, vb0, vb1, vb2, vb3;
    {
        const float4* cx = (const float4*)xr;
        va0 = cx[lane]; va1 = cx[lane + 64]; va2 = cx[lane + 128]; va3 = cx[lane + 192];
    }

#define ROW_STEP(C0, C1, C2, C3, N0, N1, N2, N3)                               \
    {                                                                          \
        if (i + 1 < nrows) {  /* prefetch next row while we reduce this one */ \
            const float4* nx = (const float4*)(xr + (size_t)(i + 1) * VV);     \
            N0 = nx[lane]; N1 = nx[lane + 64];                                 \
            N2 = nx[lane + 128]; N3 = nx[lane + 192];                          \
        }                                                                      \
        float4* sw = (float4*)srow[w];                                         \
        sw[lane] = C0; sw[lane + 64] = C1;                                     \
        sw[lane + 128] = C2; sw[lane + 192] = C3;                              \
        float m = fmaxf(fmaxf(fmaxf(C0.x, C0.y), fmaxf(C0.z, C0.w)),          \
                        fmaxf(fmaxf(C1.x, C1.y), fmaxf(C1.z, C1.w)));          \
        m = fmaxf(m, fmaxf(fmaxf(fmaxf(C2.x, C2.y), fmaxf(C2.z, C2.w)),       \
                           fmaxf(fmaxf(C3.x, C3.y), fmaxf(C3.z, C3.w))));      \
        float s = __expf(C0.x - m) + __expf(C0.y - m) + __expf(C0.z - m) +     \
                  __expf(C0.w - m) + __expf(C1.x - m) + __expf(C1.y - m) +     \
                  __expf(C1.z - m) + __expf(C1.w - m) + __expf(C2.x - m) +     \
                  __expf(C2.y - m) + __expf(C2.z - m) + __expf(C2.w - m) +     \
                  __expf(C3.x - m) + __expf(C3.y - m) + __expf(C3.z - m) +     \
                  __expf(C3.w - m);                                            \
        _Pragma("unroll")                                                      \
        for (int off = 32; off; off >>= 1) {  /* fused max+sum butterfly */    \
            const float mo = __shfl_xor(m, off);                               \
            const float so = __shfl_xor(s, off);                               \
            const float mn = fmaxf(m, mo);                                     \
            s = s * __expf(m - mn) + so * __expf(mo - mn);                     \
            m = mn;                                                            \
        }                                                                      \
        const float xbv = srow[w][0];                                          \
        const float x1v = srow[w][lab0];                                       \
        const float x3v = srow[w][lab1];                                       \
        const float pb  = __expf(xbv - m);                                     \
        ((float4*)(lpo + (size_t)i * SP))[lane] =                              \
            make_float4(pb, __expf(x1v - m), pb, __expf(x3v - m));             \
        if (lane < 16) {  /* slots 256..271 = one full 64B line */             \
            float val = 0.f;                                                   \
            if (lane == 0) val = pb;            /* state 256 (blank) */        \
            if (lane == 1) val = __logf(s);     /* LSE - mx */                 \
            lpo[(size_t)i * SP + 256 + lane] = val;                            \
        }                                                                      \
    }

    int i = 0;
    for (;;) {
        ROW_STEP(va0, va1, va2, va3, vb0, vb1, vb2, vb3)
        if (++i >= nrows) break;
        ROW_STEP(vb0, vb1, vb2, vb3, va0, va1, va2, va3)
        if (++i >= nrows) break;
    }
#undef ROW_STEP
}

// ---------------------------------------------------------------------------
// VALU-only wave64 reduces via DPP row_shr: after shr 1/2/4/8 the FULL row
// result sits in lane 15 of each 16-lane row -> combine lanes 15/31/47/63.
// bound_ctrl=true fills 0: identity-safe for add (any) and max (values >= 0).
// ---------------------------------------------------------------------------
#define DPP_ADDF(x, ctrl)                                                       \
    x = x + __int_as_float(__builtin_amdgcn_update_dpp(                         \
            0, __float_as_int(x), ctrl, 0xf, 0xf, true))
#define DPP_IMAX(x, ctrl)                                                       \
    {                                                                           \
        const int _o = __builtin_amdgcn_update_dpp(0, x, ctrl, 0xf, 0xf, true); \
        x = (x > _o) ? x : _o;                                                  \
    }
#define RLANEF(x, l) __int_as_float(__builtin_amdgcn_readlane(__float_as_int(x), (l)))
#define RLANEI(x, l) __builtin_amdgcn_readlane((x), (l))

// Full-wave shift-down-by-1 (lane l gets lane l-1; lane 0 gets +0.0) as a
// pure-VALU op: DPP wave_shr:1 (ctrl 0x138) on both halves of the double.
// bound_ctrl=1 zero-fills lane 0 -> the (lane==0 ? 0.0 : ...) mask is free.
__device__ __forceinline__ double dpp_wave_shr1_f64(double x)
{
    const int lo = __builtin_amdgcn_update_dpp(
        0, __double2loint(x), 0x138, 0xf, 0xf, true);
    const int hi = __builtin_amdgcn_update_dpp(
        0, __double2hiint(x), 0x138, 0xf, 0xf, true);
    return __hiloint2double(hi, lo);
}

// ---------------------------------------------------------------------------
// Kernel B: ONE WAVE PER BATCH, alpha in FP64 registers (4 states/lane,
// lane63 also owns state 256).
//  * __launch_bounds__(64, 1): min-1-wave/EU unlocks the full VGPR budget.
//    Round 3's VGPR_Count=36 proved the PF=8 float4 ring (32 VGPRs) was NOT
//    register-resident -- the compiler was targeting occupancy we can't use
//    (1 wave/CU anyway) and serialized the prefetch, exposing L2/L3 latency
//    every frame (~163 cy/frame vs ~75 issue-bound).
//  * PF=16 ring (64 VGPR), STATIC indices; main loop stride 16 starting at
//    t0=1 so the RNORM=16 renorm lands at static position j==15 (t0+15 is
//    always a multiple of 16) -- no runtime renorm checks in the main loop.
//  * cross-lane a3 neighbor via DPP wave_shr:1 (VALU, no DS ops).
//  * renorm: per-lane f64 max -> HI-WORD int DPP max -> EXACT 2^-k scale;
//    integer ksum replaces clog += log(m). f64 kept deliberately: the
//    state-spread below the running max can exceed f32 range.
// ---------------------------------------------------------------------------
__global__ __launch_bounds__(64, 1) void ctc_dp_kernel(
    const float* __restrict__ lp_all, const int* __restrict__ ys_pad,
    const int* __restrict__ hlens, const int* __restrict__ ys_lens,
    float* __restrict__ out)
{
    __shared__ double sh[SS];
    const int b    = blockIdx.x;
    const int lane = threadIdx.x;
    const int hl   = hlens[b];
    const float* lp = lp_all + (size_t)b * TT * SP;

    // ---- ss: sum of (LSE_t - mx_t) over t < hl, batched loads ----
    float sv[16];
#pragma unroll
    for (int jj = 0; jj < 16; ++jj)
        sv[jj] = lp[(size_t)(lane + jj * 64) * SP + 257];

    // ring prime overlaps the ss loads (hl >= 512 guarantees rows 1..PF)
    float4 qr[PF];
#pragma unroll
    for (int j = 0; j < PF; ++j)
        qr[j] = ((const float4*)(lp + (size_t)(1 + j) * SP))[lane];

    const int* lab = ys_pad + b * LM;
    const double sk1d = (lane > 0 && lab[2 * lane] != lab[2 * lane - 1]) ? 1.0 : 0.0;
    const double sk3d = (lab[2 * lane + 1] != lab[2 * lane]) ? 1.0 : 0.0;

    float ssv = 0.f;
#pragma unroll
    for (int jj = 0; jj < 16; ++jj)
        ssv += (lane + jj * 64 < hl) ? sv[jj] : 0.f;
    DPP_ADDF(ssv, 0x111); DPP_ADDF(ssv, 0x112); DPP_ADDF(ssv, 0x114); DPP_ADDF(ssv, 0x118);
    const float ssw = RLANEF(ssv, 15) + RLANEF(ssv, 31) + RLANEF(ssv, 47) + RLANEF(ssv, 63);

    // t = 0 init: only states 0 and 1 live (both in lane 0)
    const float4 q0 = ((const float4*)lp)[lane];
    double a0 = (lane == 0) ? (double)q0.x : 0.0;
    double a1 = (lane == 0) ? (double)q0.y : 0.0;
    double a2 = 0.0, a3 = 0.0, a4 = 0.0;
    int ksum = 0;

#define RENORM_BODY                                                            \
    {                                                                          \
        double m = fmax(fmax(fmax(a0, a1), fmax(a2, a3)), a4);                 \
        m = fmax(m, 1e-300);         /* denormal/zero guard */                 \
        int hi = __double2hiint(m);  /* sign=0: int cmp == mag cmp */          \
        DPP_IMAX(hi, 0x111); DPP_IMAX(hi, 0x112);                              \
        DPP_IMAX(hi, 0x114); DPP_IMAX(hi, 0x118);                              \
        const int h0 = RLANEI(hi, 15), h1 = RLANEI(hi, 31);                    \
        const int h2 = RLANEI(hi, 47), h3 = RLANEI(hi, 63);                    \
        int hw = (h0 > h1) ? h0 : h1;                                          \
        hw = (hw > h2) ? hw : h2;                                              \
        hw = (hw > h3) ? hw : h3;                                              \
        const int k = (hw >> 20) - 1022;            /* m = f*2^k, f in [0.5,1) */ \
        const double sc = __hiloint2double((1023 - k) << 20, 0); /* exact 2^-k */ \
        ksum += k;                   /* exact log tracking: ksum*ln2 */        \
        a0 *= sc; a1 *= sc; a2 *= sc; a3 *= sc; a4 *= sc;                      \
    }

#define DP_STEP(q)                                                             \
    {                                                                          \
        const double qx = (double)(q).x;                                       \
        const double qy = (double)(q).y;                                       \
        const double qw = (double)(q).w;   /* q.z == q.x (blank): no cvt */    \
        const double n1 = dpp_wave_shr1_f64(a3);  /* state 4l-1, lane0 -> 0 */ \
        const double c0 = (a0 + n1) * qx;                                      \
        const double c1 = fma(sk1d, n1, a0 + a1) * qy;                         \
        const double c2 = (a2 + a1) * qx;                                      \
        const double c3 = (a3 + fma(sk3d, a1, a2)) * qw;                       \
        const double c4 = (a4 + a3) * qx;  /* state 256; lane63 meaningful */  \
        a0 = c0; a1 = c1; a2 = c2; a3 = c3; a4 = c4;                           \
    }

    int t0 = 1;
    // main loop: stride PF=16, all frames < hl, all prefetches <= hl-1,
    // renorm at STATIC j==15 (t0+15 is always a multiple of 16).
    for (; t0 + 2 * PF - 1 <= hl - 1; t0 += PF) {
        const float* pfp = lp + (size_t)(t0 + PF) * SP;
#pragma unroll
        for (int j = 0; j < PF; ++j) {          // j static -> ring in VGPRs
            const float4 q = qr[j];
            qr[j] = ((const float4*)(pfp + (size_t)j * SP))[lane];
            if (j == PF - 1) RENORM_BODY        // t = t0+15 ≡ 0 (mod 16)
            DP_STEP(q)
        }
    }
    // tail: 16..31 frames, clamped prefetch, per-frame guards
    for (; t0 < hl; t0 += PF) {
#pragma unroll
        for (int j = 0; j < PF; ++j) {
            const int t = t0 + j;
            const float4 q = qr[j];
            int tp = t + PF; if (tp > hl - 1) tp = hl - 1;
            qr[j] = ((const float4*)(lp + (size_t)tp * SP))[lane];
            if (t < hl) {                        // wave-uniform
                if ((t & (RNORM - 1)) == 0) RENORM_BODY
                DP_STEP(q)
            }
        }
    }
#undef DP_STEP
#undef RENORM_BODY

    sh[4 * lane]     = a0;
    sh[4 * lane + 1] = a1;
    sh[4 * lane + 2] = a2;
    sh[4 * lane + 3] = a3;
    if (lane == 63) sh[256] = a4;
    __syncthreads();                             // single wave
    if (lane == 0) {
        const int L = ys_lens[b];
        const double aL = sh[2 * L] + sh[2 * L - 1];
        const double loss = (double)ssw -
            (log(aL) + (double)ksum * 0.6931471805599453);
        atomicAdd(out, (float)(loss * (1.0 / (double)BB)));
    }
}

extern "C" void kernel_launch(void* const* d_in, const int* in_sizes, int n_in,
                              void* d_out, int out_size, void* d_ws, size_t ws_size,
                              hipStream_t stream) {
    const float* ys_hat  = (const float*)d_in[0];
    const int*   ys_pad  = (const int*)d_in[1];
    const int*   hlens   = (const int*)d_in[2];
    const int*   ys_lens = (const int*)d_in[3];
    float* out = (float*)d_out;

    float* lp_raw = (float*)d_ws;        // [B, T, SP] floats (~35.7 MB)

    hipMemsetAsync(d_out, 0, sizeof(float), stream);

    ctc_row_kernel<<<BB * TT / (4 * RPW), 256, 0, stream>>>(ys_hat, ys_pad, hlens, lp_raw);
    ctc_dp_kernel<<<BB, 64, 0, stream>>>(lp_raw, ys_pad, hlens, ys_lens, out);
}

// Round 5
// 251.755 us; speedup vs baseline: 1.2812x; 1.0008x over previous
//
#include <hip/hip_runtime.h>
#include <math.h>

#define BB    32
#define TT    1024
#define VV    1024
#define LM    128
#define SS    257        // 2*LM+1 extended states
#define SP    272        // floats per row = 1088 B = 17 full cache lines
#define RNORM 16         // renormalize every 16 DP steps (f64: huge margin)
#define PF    16         // DP prefetch ring depth (STATIC indices -> registers)
#define RPW   8          // rows per wave in the row kernel

// ---------------------------------------------------------------------------
// Kernel A: one wave per 8 CONTIGUOUS rows, register double-buffered; fused
// online-softmax butterfly.  BLANK-CENTERED output (round 5): stores per lane
// the label RATIOS r = exp(x_label - x_blank) as float2 (blank prob == 1 by
// construction -> 3 of 5 DP muls vanish), plus slot 256 = LSE - x_blank.
// The per-frame max m is still used for the numerically-stable LSE butterfly
// but cancels out of the final loss entirely.  WRITE ~19 MB (was 36).
// Block 0 lane 0 also zeroes the output accumulator (replaces hipMemsetAsync).
// ---------------------------------------------------------------------------
__global__ __launch_bounds__(256) void ctc_row_kernel(
    const float* __restrict__ ys_hat, const int* __restrict__ ys_pad,
    const int* __restrict__ hlens, float* __restrict__ lp,
    float* __restrict__ out)
{
    __shared__ float srow[4][VV];
    if (blockIdx.x == 0 && threadIdx.x == 0) *out = 0.f;  // before dp runs
    const int w    = threadIdx.x >> 6;
    const int lane = threadIdx.x & 63;
    const int gw   = blockIdx.x * 4 + w;      // 0..4095 global wave id
    const int b    = gw >> 7;                 // 128 waves per batch
    const int t0   = (gw & 127) * RPW;        // first frame of this wave
    const int hl   = hlens[b];
    int nrows = hl - t0;
    if (nrows <= 0) return;                   // wave-uniform exit
    if (nrows > RPW) nrows = RPW;

    const int lab0 = ys_pad[b * LM + 2 * lane];      // label for state 4l+1
    const int lab1 = ys_pad[b * LM + 2 * lane + 1];  // label for state 4l+3
    const float* xr  = ys_hat + ((size_t)b * TT + t0) * VV;
    float*       lpo = lp     + ((size_t)b * TT + t0) * SP;

    float4 va0, va1, va2, va3, vb0, vb1, vb2, vb3;
    {
        const float4* cx = (const float4*)xr;
        va0 = cx[lane]; va1 = cx[lane + 64]; va2 = cx[lane + 128]; va3 = cx[lane + 192];
    }

#define ROW_STEP(C0, C1, C2, C3, N0, N1, N2, N3)                               \
    {                                                                          \
        if (i + 1 < nrows) {  /* prefetch next row while we reduce this one */ \
            const float4* nx = (const float4*)(xr + (size_t)(i + 1) * VV);     \
            N0 = nx[lane]; N1 = nx[lane + 64];                                 \
            N2 = nx[lane + 128]; N3 = nx[lane + 192];                          \
        }                                                                      \
        float4* sw = (float4*)srow[w];                                         \
        sw[lane] = C0; sw[lane + 64] = C1;                                     \
        sw[lane + 128] = C2; sw[lane + 192] = C3;                              \
        float m = fmaxf(fmaxf(fmaxf(C0.x, C0.y), fmaxf(C0.z, C0.w)),          \
                        fmaxf(fmaxf(C1.x, C1.y), fmaxf(C1.z, C1.w)));          \
        m = fmaxf(m, fmaxf(fmaxf(fmaxf(C2.x, C2.y), fmaxf(C2.z, C2.w)),       \
                           fmaxf(fmaxf(C3.x, C3.y), fmaxf(C3.z, C3.w))));      \
        float s = __expf(C0.x - m) + __expf(C0.y - m) + __expf(C0.z - m) +     \
                  __expf(C0.w - m) + __expf(C1.x - m) + __expf(C1.y - m) +     \
                  __expf(C1.z - m) + __expf(C1.w - m) + __expf(C2.x - m) +     \
                  __expf(C2.y - m) + __expf(C2.z - m) + __expf(C2.w - m) +     \
                  __expf(C3.x - m) + __expf(C3.y - m) + __expf(C3.z - m) +     \
                  __expf(C3.w - m);                                            \
        _Pragma("unroll")                                                      \
        for (int off = 32; off; off >>= 1) {  /* fused max+sum butterfly */    \
            const float mo = __shfl_xor(m, off);                               \
            const float so = __shfl_xor(s, off);                               \
            const float mn = fmaxf(m, mo);                                     \
            s = s * __expf(m - mn) + so * __expf(mo - mn);                     \
            m = mn;                                                            \
        }                                                                      \
        const float xbv = srow[w][0];                                          \
        const float x1v = srow[w][lab0];                                       \
        const float x3v = srow[w][lab1];                                       \
        ((float2*)(lpo + (size_t)i * SP))[lane] =                              \
            make_float2(__expf(x1v - xbv), __expf(x3v - xbv));                 \
        if (lane < 16) {  /* slots 256..271 = one full 64B line */             \
            float val = 0.f;                                                   \
            if (lane == 0) val = __logf(s) + (m - xbv);  /* LSE - x_blank */   \
            lpo[(size_t)i * SP + 256 + lane] = val;                            \
        }                                                                      \
    }

    int i = 0;
    for (;;) {
        ROW_STEP(va0, va1, va2, va3, vb0, vb1, vb2, vb3)
        if (++i >= nrows) break;
        ROW_STEP(vb0, vb1, vb2, vb3, va0, va1, va2, va3)
        if (++i >= nrows) break;
    }
#undef ROW_STEP
}

// ---------------------------------------------------------------------------
// VALU-only wave64 reduces via DPP row_shr: after shr 1/2/4/8 the FULL row
// result sits in lane 15 of each 16-lane row -> combine lanes 15/31/47/63.
// bound_ctrl=true fills 0: identity-safe for add (any) and max (values >= 0).
// ---------------------------------------------------------------------------
#define DPP_ADDF(x, ctrl)                                                       \
    x = x + __int_as_float(__builtin_amdgcn_update_dpp(                         \
            0, __float_as_int(x), ctrl, 0xf, 0xf, true))
#define DPP_IMAX(x, ctrl)                                                       \
    {                                                                           \
        const int _o = __builtin_amdgcn_update_dpp(0, x, ctrl, 0xf, 0xf, true); \
        x = (x > _o) ? x : _o;                                                  \
    }
#define RLANEF(x, l) __int_as_float(__builtin_amdgcn_readlane(__float_as_int(x), (l)))
#define RLANEI(x, l) __builtin_amdgcn_readlane((x), (l))

// Full-wave shift-down-by-1 (lane l gets lane l-1; lane 0 gets +0.0) as a
// pure-VALU op: DPP wave_shr:1 (ctrl 0x138) on both halves of the double.
// bound_ctrl=1 zero-fills lane 0 -> the (lane==0 ? 0.0 : ...) mask is free.
__device__ __forceinline__ double dpp_wave_shr1_f64(double x)
{
    const int lo = __builtin_amdgcn_update_dpp(
        0, __double2loint(x), 0x138, 0xf, 0xf, true);
    const int hi = __builtin_amdgcn_update_dpp(
        0, __double2hiint(x), 0x138, 0xf, 0xf, true);
    return __hiloint2double(hi, lo);
}

// ---------------------------------------------------------------------------
// Kernel B: ONE WAVE PER BATCH, beta (= alpha / prod_t p_blank(t)) in FP64
// registers, 4 states/lane + state 256 on lane 63.  Blank-centered DP:
//   c0 = b0 + n1                       (blank states: NO multiply)
//   c1 = (b0 + b1 + sk1*n1) * ry       (ry = exp(x_lab0 - x_blank))
//   c2 = b2 + b1
//   c3 = (b3 + b2 + sk3*b1) * rw
//   c4 = b4 + b3
// 9 f64 ops + 2 cvt per frame (was 12 + 3).  Loss telescopes to
//   loss = sum_t(LSE_t - x_blank,t) - log(bL) - ksum*ln2   (max m cancels).
// Renorm every 16 frames: hi-word int DPP max -> EXACT 2^±k scale, integer
// ksum tracking; beta drift per interval <= e^±176, far inside f64 range;
// relative state spread identical to the max-centered variant (recentering
// is a uniform per-frame scalar), so f64 safety is unchanged.
// __launch_bounds__(64,1) keeps the PF=16 float2 ring (32 VGPR) in registers.
// ---------------------------------------------------------------------------
__global__ __launch_bounds__(64, 1) void ctc_dp_kernel(
    const float* __restrict__ lp_all, const int* __restrict__ ys_pad,
    const int* __restrict__ hlens, const int* __restrict__ ys_lens,
    float* __restrict__ out)
{
    __shared__ double sh[SS];
    const int b    = blockIdx.x;
    const int lane = threadIdx.x;
    const int hl   = hlens[b];
    const float* lp = lp_all + (size_t)b * TT * SP;

    // ---- ss: sum of (LSE_t - x_blank,t) over t < hl, batched loads ----
    float sv[16];
#pragma unroll
    for (int jj = 0; jj < 16; ++jj)
        sv[jj] = lp[(size_t)(lane + jj * 64) * SP + 256];

    // ring prime overlaps the ss loads (hl >= 512 guarantees rows 1..PF)
    float2 qr[PF];
#pragma unroll
    for (int j = 0; j < PF; ++j)
        qr[j] = ((const float2*)(lp + (size_t)(1 + j) * SP))[lane];

    const int* lab = ys_pad + b * LM;
    const double sk1d = (lane > 0 && lab[2 * lane] != lab[2 * lane - 1]) ? 1.0 : 0.0;
    const double sk3d = (lab[2 * lane + 1] != lab[2 * lane]) ? 1.0 : 0.0;

    float ssv = 0.f;
#pragma unroll
    for (int jj = 0; jj < 16; ++jj)
        ssv += (lane + jj * 64 < hl) ? sv[jj] : 0.f;
    DPP_ADDF(ssv, 0x111); DPP_ADDF(ssv, 0x112); DPP_ADDF(ssv, 0x114); DPP_ADDF(ssv, 0x118);
    const float ssw = RLANEF(ssv, 15) + RLANEF(ssv, 31) + RLANEF(ssv, 47) + RLANEF(ssv, 63);

    // t = 0 init in beta-units (divide by p_blank(0)): b0 = 1, b1 = ry(0)
    const float2 q0 = ((const float2*)lp)[lane];
    double a0 = (lane == 0) ? 1.0 : 0.0;
    double a1 = (lane == 0) ? (double)q0.x : 0.0;
    double a2 = 0.0, a3 = 0.0, a4 = 0.0;
    int ksum = 0;

#define RENORM_BODY                                                            \
    {                                                                          \
        double m = fmax(fmax(fmax(a0, a1), fmax(a2, a3)), a4);                 \
        m = fmax(m, 1e-300);         /* denormal/zero guard */                 \
        int hi = __double2hiint(m);  /* sign=0: int cmp == mag cmp */          \
        DPP_IMAX(hi, 0x111); DPP_IMAX(hi, 0x112);                              \
        DPP_IMAX(hi, 0x114); DPP_IMAX(hi, 0x118);                              \
        const int h0 = RLANEI(hi, 15), h1 = RLANEI(hi, 31);                    \
        const int h2 = RLANEI(hi, 47), h3 = RLANEI(hi, 63);                    \
        int hw = (h0 > h1) ? h0 : h1;                                          \
        hw = (hw > h2) ? hw : h2;                                              \
        hw = (hw > h3) ? hw : h3;                                              \
        const int k = (hw >> 20) - 1022;            /* m = f*2^k, f in [0.5,1) */ \
        const double sc = __hiloint2double((1023 - k) << 20, 0); /* exact 2^-k */ \
        ksum += k;                   /* exact log tracking: ksum*ln2 */        \
        a0 *= sc; a1 *= sc; a2 *= sc; a3 *= sc; a4 *= sc;                      \
    }

#define DP_STEP(q)                                                             \
    {                                                                          \
        const double ry = (double)(q).x;   /* exp(x_lab0 - x_blank) */         \
        const double rw = (double)(q).y;   /* exp(x_lab1 - x_blank) */         \
        const double n1 = dpp_wave_shr1_f64(a3);  /* state 4l-1, lane0 -> 0 */ \
        const double c0 = a0 + n1;                       /* blank: no mul */   \
        const double c1 = fma(sk1d, n1, a0 + a1) * ry;                         \
        const double c2 = a2 + a1;                       /* blank: no mul */   \
        const double c3 = (a3 + fma(sk3d, a1, a2)) * rw;                       \
        const double c4 = a4 + a3;         /* state 256 (blank); lane63 */     \
        a0 = c0; a1 = c1; a2 = c2; a3 = c3; a4 = c4;                           \
    }

    int t0 = 1;
    // main loop: stride PF=16, all frames < hl, all prefetches <= hl-1,
    // renorm at STATIC j==15 (t0+15 is always a multiple of 16).
    for (; t0 + 2 * PF - 1 <= hl - 1; t0 += PF) {
        const float* pfp = lp + (size_t)(t0 + PF) * SP;
#pragma unroll
        for (int j = 0; j < PF; ++j) {          // j static -> ring in VGPRs
            const float2 q = qr[j];
            qr[j] = ((const float2*)(pfp + (size_t)j * SP))[lane];
            if (j == PF - 1) RENORM_BODY        // t = t0+15 ≡ 0 (mod 16)
            DP_STEP(q)
        }
    }
    // tail: 16..31 frames, clamped prefetch, per-frame guards
    for (; t0 < hl; t0 += PF) {
#pragma unroll
        for (int j = 0; j < PF; ++j) {
            const int t = t0 + j;
            const float2 q = qr[j];
            int tp = t + PF; if (tp > hl - 1) tp = hl - 1;
            qr[j] = ((const float2*)(lp + (size_t)tp * SP))[lane];
            if (t < hl) {                        // wave-uniform
                if ((t & (RNORM - 1)) == 0) RENORM_BODY
                DP_STEP(q)
            }
        }
    }
#undef DP_STEP
#undef RENORM_BODY

    sh[4 * lane]     = a0;
    sh[4 * lane + 1] = a1;
    sh[4 * lane + 2] = a2;
    sh[4 * lane + 3] = a3;
    if (lane == 63) sh[256] = a4;
    __syncthreads();                             // single wave
    if (lane == 0) {
        const int L = ys_lens[b];
        const double aL = sh[2 * L] + sh[2 * L - 1];
        const double loss = (double)ssw -
            (log(aL) + (double)ksum * 0.6931471805599453);
        atomicAdd(out, (float)(loss * (1.0 / (double)BB)));
    }
}

extern "C" void kernel_launch(void* const* d_in, const int* in_sizes, int n_in,
                              void* d_out, int out_size, void* d_ws, size_t ws_size,
                              hipStream_t stream) {
    const float* ys_hat  = (const float*)d_in[0];
    const int*   ys_pad  = (const int*)d_in[1];
    const int*   hlens   = (const int*)d_in[2];
    const int*   ys_lens = (const int*)d_in[3];
    float* out = (float*)d_out;

    float* lp_raw = (float*)d_ws;        // [B, T, SP] floats (~35.7 MB)

    // out is zeroed by ctc_row_kernel block 0 (stream-ordered before dp).
    ctc_row_kernel<<<BB * TT / (4 * RPW), 256, 0, stream>>>(ys_hat, ys_pad, hlens, lp_raw, out);
    ctc_dp_kernel<<<BB, 64, 0, stream>>>(lp_raw, ys_pad, hlens, ys_lens, out);
}